// Round 2
// baseline (237.336 us; speedup 1.0000x reference)
//
#include <hip/hip_runtime.h>

#define HIDDEN 64
#define SEQLEN 96
#define NB 10
#define BATCH 16384
#define NCLASS 2
#define BT 64                       // batch tile per block (= lanes per wave)
#define NWAVES 16                   // waves per block, each owns IPW i-values
#define IPW (HIDDEN / NWAVES)       // 4 i's per wave
#define RSTRIDE (HIDDEN + 1)        // +1 pad: bank (b+o)%32 -> 2-way (free)

// tanh(x) = 1 - 2/(e^{2x}+1); saturates correctly for large |x|.
__device__ __forceinline__ float fast_tanh(float x) {
    float e = __expf(x + x);
    float r = __builtin_amdgcn_rcpf(e + 1.0f);
    return fmaf(-2.0f, r, 1.0f);
}

__global__ __launch_bounds__(BT * NWAVES, 4) void kan_fused(
    const float* __restrict__ x,    // (B, SEQLEN)
    const float* __restrict__ Wx,   // (1, HIDDEN, NB)
    const float* __restrict__ ax,   // (1, NB)
    const float* __restrict__ cx,   // (1, NB)
    const float* __restrict__ Wc,   // (HIDDEN, HIDDEN, NB)
    const float* __restrict__ ac,   // (HIDDEN, NB)
    const float* __restrict__ cc,   // (HIDDEN, NB)
    const float* __restrict__ Wout, // (HIDDEN, NCLASS)
    float* __restrict__ out)        // (B, NCLASS)
{
    __shared__ float red[BT * RSTRIDE];
    __shared__ float outb[BT * NCLASS];

    const int lane = threadIdx.x;           // batch lane 0..63 (fast dim -> one wave per y)
    const int wid  = threadIdx.y;           // wave id 0..15 -> i-group (wave-uniform)
    const int tid  = wid * BT + lane;
    const int gb   = blockIdx.x * BT + lane;

    for (int idx = tid; idx < BT * RSTRIDE; idx += BT * NWAVES)
        red[idx] = 0.0f;
    if (tid < BT * NCLASS) outb[tid] = 0.0f;
    __syncthreads();

    // ---- stage 1: recurrence is dead; h depends only on x[:, 95] ----
    const float u = x[gb * SEQLEN + (SEQLEN - 1)];
    float t[NB];
#pragma unroll
    for (int k = 0; k < NB; ++k)
        t[k] = fast_tanh(fmaf(ax[k], u, cx[k]));

    float acc[HIDDEN];
#pragma unroll
    for (int o = 0; o < HIDDEN; ++o) acc[o] = 0.0f;

#pragma unroll 1                            // keep body in I$; 4 iterations
    for (int ii = 0; ii < IPW; ++ii) {
        const int i = wid * IPW + ii;       // wave-uniform -> s_load weights
        const float* wxr = Wx + i * NB;
        float hx = 0.0f;
#pragma unroll
        for (int k = 0; k < NB; ++k)
            hx = fmaf(wxr[k], t[k], hx);
        const float hi = fast_tanh(hx);

        const float* acr = ac + i * NB;
        const float* ccr = cc + i * NB;
        float p[NB];
#pragma unroll
        for (int k = 0; k < NB; ++k)
            p[k] = fast_tanh(fmaf(acr[k], hi, ccr[k]));

        const float* wcr = Wc + i * (HIDDEN * NB);
#pragma unroll
        for (int o = 0; o < HIDDEN; ++o) {  // 64 independent acc chains (ILP)
#pragma unroll
            for (int k = 0; k < NB; ++k)
                acc[o] = fmaf(wcr[o * NB + k], p[k], acc[o]);
        }
    }

    // ---- cross-wave reduction of acc over the 16 i-groups ----
#pragma unroll
    for (int o = 0; o < HIDDEN; ++o)
        atomicAdd(&red[lane * RSTRIDE + o], acc[o]);
    __syncthreads();

    // ---- epilogue: g = tanh(sum), out = g @ Wout; wave wid owns 4 o's ----
    float r0 = 0.0f, r1 = 0.0f;
#pragma unroll
    for (int j = 0; j < IPW; ++j) {
        const int o = wid * IPW + j;        // wave-uniform -> Wout via s_load
        const float g = fast_tanh(red[lane * RSTRIDE + o]);
        r0 = fmaf(g, Wout[o * NCLASS + 0], r0);
        r1 = fmaf(g, Wout[o * NCLASS + 1], r1);
    }
    atomicAdd(&outb[lane * NCLASS + 0], r0);
    atomicAdd(&outb[lane * NCLASS + 1], r1);
    __syncthreads();

    if (tid < BT * NCLASS)
        out[blockIdx.x * (BT * NCLASS) + tid] = outb[tid];   // coalesced
}

extern "C" void kernel_launch(void* const* d_in, const int* in_sizes, int n_in,
                              void* d_out, int out_size, void* d_ws, size_t ws_size,
                              hipStream_t stream) {
    const float* x    = (const float*)d_in[0];
    const float* Wx   = (const float*)d_in[1];
    const float* ax   = (const float*)d_in[2];
    const float* cx   = (const float*)d_in[3];
    // d_in[4..6] = Wh, ah, ch — dead (comb[:, :HIDDEN] == tanh(x_phi))
    const float* Wc   = (const float*)d_in[7];
    const float* ac   = (const float*)d_in[8];
    const float* cc   = (const float*)d_in[9];
    const float* Wout = (const float*)d_in[10];
    float* out = (float*)d_out;

    dim3 grid(BATCH / BT);                  // 256 blocks, 1 per CU
    dim3 block(BT, NWAVES);                 // 1024 threads = 16 waves
    kan_fused<<<grid, block, 0, stream>>>(x, Wx, ax, cx, Wc, ac, cc, Wout, out);
}

// Round 3
// 101.976 us; speedup vs baseline: 2.3274x; 2.3274x over previous
//
#include <hip/hip_runtime.h>

#define HIDDEN 64
#define SEQLEN 96
#define NB 10
#define BATCH 16384
#define NCLASS 2
#define KTOT (HIDDEN * NB)   // 640
#define NKC (KTOT / 32)      // 20 K-chunks of 32
#define MT 16                // batch rows per block
#define NW 4                 // waves per block = K-split factor
#define KCW (NKC / NW)       // 5 K-chunks per wave

typedef __attribute__((ext_vector_type(8))) short bf16x8;
typedef __attribute__((ext_vector_type(4))) float f32x4;

__device__ __forceinline__ float fast_tanh(float x) {
    float e = __expf(x + x);
    float r = __builtin_amdgcn_rcpf(e + 1.0f);
    return fmaf(-2.0f, r, 1.0f);
}

__device__ __forceinline__ unsigned bf16_rn(float f) {
    unsigned u = __float_as_uint(f);
    return (u + 0x8000u) >> 16;   // round-half-up; values are tame (no inf/nan)
}

// Repack Wc (HIDDEN,HIDDEN,NB) fp32 -> bf16 B-fragments for 16x16x32 MFMA.
// Layout: Wp[((kcg*4 + nt)*64 + lane)*8 + j] = bf16(W[q][o]),
//   q = kcg*32 + (lane>>4)*8 + j, o = nt*16 + (lane&15), W[q][o] = Wc[q/10][o][q%10]
__global__ __launch_bounds__(256) void prep_wb(const float* __restrict__ Wc,
                                               ushort* __restrict__ Wp) {
    int e = blockIdx.x * 256 + threadIdx.x;      // 0..40959
    int j = e & 7;
    int lane = (e >> 3) & 63;
    int rest = e >> 9;                            // kcg*4 + nt, 0..79
    int nt = rest & 3;
    int kcg = rest >> 2;
    int q = kcg * 32 + (lane >> 4) * 8 + j;
    int o = nt * 16 + (lane & 15);
    int i = q / 10;
    int k = q - i * 10;
    Wp[e] = (ushort)bf16_rn(Wc[i * (HIDDEN * NB) + o * NB + k]);
}

__global__ __launch_bounds__(256, 4) void kan_mfma(
    const float* __restrict__ x,    // (B, SEQLEN)
    const float* __restrict__ Wx,   // (1, HIDDEN, NB)
    const float* __restrict__ ax, const float* __restrict__ cx,  // (1, NB)
    const float* __restrict__ ac,   // (HIDDEN, NB) flat == q-order
    const float* __restrict__ cc,   // (HIDDEN, NB) flat == q-order
    const float* __restrict__ Wout, // (HIDDEN, NCLASS)
    const ushort* __restrict__ Wp,  // packed B-fragments (d_ws)
    float* __restrict__ out)        // (B, NCLASS)
{
    __shared__ float hs[65 * 16];        // h[i][m], +1 row guard for i0+1 read
    __shared__ float Cred[16 * 64];      // K-split reduction of C
    __shared__ float outb[MT * NCLASS];

    const int lane = threadIdx.x;        // 0..63
    const int w    = threadIdx.y;        // 0..3  (K-split wave id)
    const int tid  = w * 64 + lane;
    const int bb   = blockIdx.x * MT;

    for (int idx = tid; idx < 16 * 64; idx += 256) Cred[idx] = 0.0f;

    // ---- stage A: h[i][m] = tanh(Wx_row_i . t_m); recurrence dead, only x[:,95] matters
    {
        const int sm = tid & 15;         // batch row
        const int sg = tid >> 4;         // i-group: 4 i's per thread, shared t
        const float u = x[(bb + sm) * SEQLEN + (SEQLEN - 1)];
        float t[NB];
#pragma unroll
        for (int k = 0; k < NB; ++k)
            t[k] = fast_tanh(fmaf(ax[k], u, cx[k]));
#pragma unroll
        for (int r = 0; r < 4; ++r) {
            const int i = sg * 4 + r;
            const float* wxr = Wx + i * NB;
            float hx = 0.0f;
#pragma unroll
            for (int k = 0; k < NB; ++k)
                hx = fmaf(wxr[k], t[k], hx);
            hs[i * 16 + sm] = fast_tanh(hx);
        }
    }
    __syncthreads();

    // ---- stage B: 16384x640x64 GEMM via MFMA; wave w owns K-chunks [w*5, w*5+5)
    const int m    = lane & 15;          // A-operand row (batch)
    const int quad = lane >> 4;
    f32x4 acc0 = {0,0,0,0}, acc1 = {0,0,0,0}, acc2 = {0,0,0,0}, acc3 = {0,0,0,0};

#pragma unroll
    for (int c = 0; c < KCW; ++c) {
        const int kcg = w * KCW + c;
        const int q0  = kcg * 32 + quad * 8;   // lane's first q of this chunk
        const int i0  = q0 / 10;               // magic-mul div by const
        const int r0  = q0 - i0 * 10;
        const float h0 = hs[i0 * 16 + m];
        const float h1 = hs[(i0 + 1) * 16 + m];  // guard row; never selected OOB
        const float4 a0 = *(const float4*)(ac + q0);
        const float4 a1 = *(const float4*)(ac + q0 + 4);
        const float4 c0 = *(const float4*)(cc + q0);
        const float4 c1 = *(const float4*)(cc + q0 + 4);
        const float av[8] = {a0.x,a0.y,a0.z,a0.w,a1.x,a1.y,a1.z,a1.w};
        const float cv[8] = {c0.x,c0.y,c0.z,c0.w,c1.x,c1.y,c1.z,c1.w};
        float p[8];
#pragma unroll
        for (int j = 0; j < 8; ++j) {
            const float hj = (r0 + j >= 10) ? h1 : h0;   // i crosses at most once per octet
            p[j] = fast_tanh(fmaf(av[j], hj, cv[j]));
        }
        union { unsigned u[4]; bf16x8 v; } af;
#pragma unroll
        for (int jj = 0; jj < 4; ++jj)
            af.u[jj] = bf16_rn(p[2 * jj]) | (bf16_rn(p[2 * jj + 1]) << 16);

        const ushort* wb = Wp + (size_t)(kcg * 4) * 512 + lane * 8;
        const bf16x8 b0 = *(const bf16x8*)(wb);
        const bf16x8 b1 = *(const bf16x8*)(wb + 512);
        const bf16x8 b2 = *(const bf16x8*)(wb + 1024);
        const bf16x8 b3 = *(const bf16x8*)(wb + 1536);
        acc0 = __builtin_amdgcn_mfma_f32_16x16x32_bf16(af.v, b0, acc0, 0, 0, 0);
        acc1 = __builtin_amdgcn_mfma_f32_16x16x32_bf16(af.v, b1, acc1, 0, 0, 0);
        acc2 = __builtin_amdgcn_mfma_f32_16x16x32_bf16(af.v, b2, acc2, 0, 0, 0);
        acc3 = __builtin_amdgcn_mfma_f32_16x16x32_bf16(af.v, b3, acc3, 0, 0, 0);
    }

    // ---- K-split combine: C/D layout col=lane&15, row=quad*4+reg
#pragma unroll
    for (int reg = 0; reg < 4; ++reg) {
        const int row = quad * 4 + reg;
        atomicAdd(&Cred[row * 64 +  0 + m], acc0[reg]);
        atomicAdd(&Cred[row * 64 + 16 + m], acc1[reg]);
        atomicAdd(&Cred[row * 64 + 32 + m], acc2[reg]);
        atomicAdd(&Cred[row * 64 + 48 + m], acc3[reg]);
    }
    __syncthreads();

    // ---- epilogue: g = tanh(C), out = g @ Wout
    {
        const int mm = tid >> 4;         // batch row 0..15 (16 consecutive lanes share)
        const int ob = (tid & 15) * 4;   // 4 o's per thread
        float r0 = 0.0f, r1 = 0.0f;
#pragma unroll
        for (int t2 = 0; t2 < 4; ++t2) {
            const int o = ob + t2;
            const float g = fast_tanh(Cred[mm * 64 + o]);
            r0 = fmaf(g, Wout[o * NCLASS + 0], r0);
            r1 = fmaf(g, Wout[o * NCLASS + 1], r1);
        }
#pragma unroll
        for (int off = 8; off > 0; off >>= 1) {
            r0 += __shfl_down(r0, off, 16);
            r1 += __shfl_down(r1, off, 16);
        }
        if ((tid & 15) == 0) {
            outb[mm * NCLASS + 0] = r0;
            outb[mm * NCLASS + 1] = r1;
        }
    }
    __syncthreads();
    if (tid < MT * NCLASS)
        out[bb * NCLASS + tid] = outb[tid];   // coalesced 32-dword store
}

extern "C" void kernel_launch(void* const* d_in, const int* in_sizes, int n_in,
                              void* d_out, int out_size, void* d_ws, size_t ws_size,
                              hipStream_t stream) {
    const float* x    = (const float*)d_in[0];
    const float* Wx   = (const float*)d_in[1];
    const float* ax   = (const float*)d_in[2];
    const float* cx   = (const float*)d_in[3];
    // d_in[4..6] = Wh, ah, ch — dead (comb[:, :HIDDEN] == tanh(x_phi))
    const float* Wc   = (const float*)d_in[7];
    const float* ac   = (const float*)d_in[8];
    const float* cc   = (const float*)d_in[9];
    const float* Wout = (const float*)d_in[10];
    float* out  = (float*)d_out;
    ushort* Wp  = (ushort*)d_ws;    // 40960 bf16 = 80 KiB

    prep_wb<<<dim3(NKC * 4 * 512 / 256), dim3(256), 0, stream>>>(Wc, Wp);
    kan_mfma<<<dim3(BATCH / MT), dim3(64, NW), 0, stream>>>(
        x, Wx, ax, cx, ac, cc, Wout, Wp, out);
}